// Round 1
// 518.186 us; speedup vs baseline: 1.0005x; 1.0005x over previous
//
#include <hip/hip_runtime.h>

#define NN 512
#define DD 128
#define PP (NN*NN)   // 262144 positions

typedef __attribute__((ext_vector_type(8))) short short8;
typedef __attribute__((ext_vector_type(4))) float floatx4;
typedef __attribute__((ext_vector_type(4))) unsigned int uintx4;

__device__ __forceinline__ unsigned short f2bf(float f) {
  unsigned int u = __float_as_uint(f);
  u += 0x7fffu + ((u >> 16) & 1u);          // RNE
  return (unsigned short)(u >> 16);
}
// packed f32x2 -> bf16x2 (hardware RNE), low half <- first arg
__device__ __forceinline__ unsigned int pkbf2(float lo, float hi) {
  unsigned int r;
  asm("v_cvt_pk_bf16_f32 %0, %1, %2" : "=v"(r) : "v"(lo), "v"(hi));
  return r;
}
__device__ __forceinline__ float sigm(float x) {
  return 1.f / (1.f + __expf(-x));
}

// async global->LDS, 16B per lane. LDS dest must be wave-uniform base + lane*16.
__device__ __forceinline__ void gload_lds16(const unsigned short* g, unsigned short* l) {
  __builtin_amdgcn_global_load_lds(
      (const __attribute__((address_space(1))) unsigned int*)g,
      (__attribute__((address_space(3))) unsigned int*)l, 16, 0, 0);
}

// ---------------- k0: weights f32 [d][e] -> bf16 [m][e][d] ----------------
__global__ void k0_prep(const float* __restrict__ wlp, const float* __restrict__ wlg,
                        const float* __restrict__ wrp, const float* __restrict__ wrg,
                        const float* __restrict__ wg,  const float* __restrict__ wo,
                        unsigned short* __restrict__ wt) {
  const float* src[6] = {wlp, wlg, wrp, wrg, wg, wo};
  int m = blockIdx.y;
  int idx = blockIdx.x * 256 + threadIdx.x;   // 0..16383
  int d = idx >> 7, e = idx & 127;
  wt[m * 16384 + e * 128 + d] = f2bf(src[m][d * 128 + e]);
}

// ---------------- k1a: LayerNorm pair f32 -> xln bf16 [p][d] -----------------
__launch_bounds__(256, 4)
__global__ void k1a_ln(const float* __restrict__ pair,
                       const float* __restrict__ lng, const float* __restrict__ lnb,
                       unsigned short* __restrict__ xln) {
  const int t = threadIdx.x;
  const long p0 = (long)blockIdx.x << 7;
  const int r = t >> 1, h = t & 1;
  const float* row = pair + (p0 + r) * DD + h * 64;
  floatx4 v[16];
  float s = 0.f, s2 = 0.f;
  #pragma unroll
  for (int c = 0; c < 16; ++c) {
    v[c] = *(const floatx4*)(row + c * 4);
    s  += v[c].x + v[c].y + v[c].z + v[c].w;
    s2 += v[c].x * v[c].x + v[c].y * v[c].y + v[c].z * v[c].z + v[c].w * v[c].w;
  }
  s  += __shfl_xor(s, 1);
  s2 += __shfl_xor(s2, 1);
  float mu = s * (1.f / 128.f);
  float var = s2 * (1.f / 128.f) - mu * mu;
  float rs = rsqrtf(var + 1e-5f);
  unsigned short* orow = xln + (p0 + r) * DD + h * 64;
  #pragma unroll
  for (int c2 = 0; c2 < 8; ++c2) {
    floatx4 g0 = *(const floatx4*)(lng + h * 64 + c2 * 8);
    floatx4 g1 = *(const floatx4*)(lng + h * 64 + c2 * 8 + 4);
    floatx4 b0 = *(const floatx4*)(lnb + h * 64 + c2 * 8);
    floatx4 b1 = *(const floatx4*)(lnb + h * 64 + c2 * 8 + 4);
    floatx4 a = v[2 * c2], b = v[2 * c2 + 1];
    uintx4 u;
    u[0] = pkbf2((a.x - mu) * rs * g0.x + b0.x, (a.y - mu) * rs * g0.y + b0.y);
    u[1] = pkbf2((a.z - mu) * rs * g0.z + b0.z, (a.w - mu) * rs * g0.w + b0.w);
    u[2] = pkbf2((b.x - mu) * rs * g1.x + b1.x, (b.y - mu) * rs * g1.y + b1.y);
    u[3] = pkbf2((b.z - mu) * rs * g1.z + b1.z, (b.w - mu) * rs * g1.w + b1.w);
    *(uintx4*)(orow + c2 * 8) = u;
  }
}

// ---------------- k1b: projections, staged GEMM, 512 threads / 8 waves -------
// unit 0: left_t[e][p], unit 1: right_bt[e][k*512+j], unit 2: gate_t[e][p]
// 8 waves, each owns a 64(m) x 32(e) output subtile -> acc = 64 unified VGPRs
// (vs 128 before) so 4 waves/SIMD fit: occupancy 8 -> 16 waves/CU.
__launch_bounds__(512, 4)
__global__ void k1b_proj(const unsigned short* __restrict__ xln,
                         const float* __restrict__ pmask,
                         const unsigned short* __restrict__ wt,
                         const float* __restrict__ b_lp, const float* __restrict__ b_lg,
                         const float* __restrict__ b_rp, const float* __restrict__ b_rg,
                         const float* __restrict__ b_g,
                         unsigned short* __restrict__ left_t,
                         unsigned short* __restrict__ right_bt,
                         unsigned short* __restrict__ gate_t) {
  __shared__ __align__(16) unsigned short Sm[17408];  // Al/Bp/Bg, overlaid by stg
  __shared__ float Mlds[128];
  unsigned short* Al = Sm;            // 128x32
  unsigned short* Bp = Sm + 4096;     // 128x32
  unsigned short* Bg = Sm + 8192;     // 128x32

  const int t = threadIdx.x;
  const int unit = blockIdx.y;
  const int q = blockIdx.x;

  int j0 = 0, kk = 0;
  long p0 = 0, soff;
  if (unit == 1) {
    j0 = (q >> 9) << 7; kk = q & 511;
    soff = (long)kk * NN + j0;
  } else {
    p0 = (long)q << 7;
    soff = p0;
  }
  auto arow = [&](int r) -> long {
    return (unit == 1) ? ((long)(j0 + r) * NN + kk) : (p0 + r);
  };

  if (unit < 2 && t < 128) Mlds[t] = pmask[arow(t)];

  const unsigned short* wA = wt + (unit == 0 ? 0 : unit == 1 ? 2 : 4) * 16384;
  const unsigned short* wB = wt + (unit == 0 ? 1 : 3) * 16384;  // unused for unit 2

  const int lane = t & 63, w = t >> 6;            // 8 waves
  const int ln = lane & 15, q8 = lane >> 4;
  const int wm = (w >> 2) << 6, we = (w & 3) << 5; // 64x32 per-wave tile
  const int sr = t >> 2, sc = t & 3;               // staging: one 16B chunk/thread

  floatx4 aP[4][2] = {}, aG[4][2] = {};
  for (int kc = 0; kc < 4; ++kc) {
    gload_lds16(xln + arow(sr) * DD + kc * 32 + sc * 8, &Al[t * 8]);
    gload_lds16(wA + sr * 128 + kc * 32 + sc * 8,       &Bp[t * 8]);
    if (unit < 2)
      gload_lds16(wB + sr * 128 + kc * 32 + sc * 8,     &Bg[t * 8]);
    __syncthreads();
    short8 a[4];
    #pragma unroll
    for (int i = 0; i < 4; ++i)
      a[i] = *(const short8*)&Al[(wm + i * 16 + ln) * 32 + q8 * 8];
    #pragma unroll
    for (int j = 0; j < 2; ++j) {
      short8 bpv = *(const short8*)&Bp[(we + j * 16 + ln) * 32 + q8 * 8];
      #pragma unroll
      for (int i = 0; i < 4; ++i)
        aP[i][j] = __builtin_amdgcn_mfma_f32_16x16x32_bf16(a[i], bpv, aP[i][j], 0, 0, 0);
    }
    if (unit < 2) {
      #pragma unroll
      for (int j = 0; j < 2; ++j) {
        short8 bgv = *(const short8*)&Bg[(we + j * 16 + ln) * 32 + q8 * 8];
        #pragma unroll
        for (int i = 0; i < 4; ++i)
          aG[i][j] = __builtin_amdgcn_mfma_f32_16x16x32_bf16(a[i], bgv, aG[i][j], 0, 0, 0);
      }
    }
    __syncthreads();
  }

  // epilogue -> per-wave stg (32 e-rows x 64 m-cols, pitch 68) -> coalesced store
  unsigned short* mystg = Sm + w * 2176;
  if (unit < 2) {
    const float* bpp = (unit == 0) ? b_lp : b_rp;
    const float* bgg = (unit == 0) ? b_lg : b_rg;
    #pragma unroll
    for (int j = 0; j < 2; ++j) {
      int eg = we + j * 16 + ln;
      float bp = bpp[eg], bg = bgg[eg];
      #pragma unroll
      for (int i = 0; i < 4; ++i) {
        float vv[4];
        #pragma unroll
        for (int r = 0; r < 4; ++r) {
          int m = wm + i * 16 + q8 * 4 + r;
          vv[r] = (aP[i][j][r] + bp) * sigm(aG[i][j][r] + bg) * Mlds[m];
        }
        unsigned int* du = (unsigned int*)&mystg[(j * 16 + ln) * 68 + i * 16 + q8 * 4];
        du[0] = pkbf2(vv[0], vv[1]);
        du[1] = pkbf2(vv[2], vv[3]);
      }
    }
  } else {
    #pragma unroll
    for (int j = 0; j < 2; ++j) {
      int eg = we + j * 16 + ln;
      float bg = b_g[eg];
      #pragma unroll
      for (int i = 0; i < 4; ++i) {
        float vv[4];
        #pragma unroll
        for (int r = 0; r < 4; ++r)
          vv[r] = sigm(aP[i][j][r] + bg);
        unsigned int* du = (unsigned int*)&mystg[(j * 16 + ln) * 68 + i * 16 + q8 * 4];
        du[0] = pkbf2(vv[0], vv[1]);
        du[1] = pkbf2(vv[2], vv[3]);
      }
    }
  }

  unsigned short* dstbase = (unit == 0) ? left_t : (unit == 1 ? right_bt : gate_t);
  #pragma unroll
  for (int itr = 0; itr < 4; ++itr) {       // coalesced transposed store: rows = e
    int row = itr * 8 + (lane >> 3);        // 0..31
    int c = lane & 7;
    short8 vv = *(const short8*)&mystg[row * 68 + c * 8];
    long eg = we + row;
    *(short8*)(dstbase + eg * PP + soff + wm + c * 8) = vv;
  }
}

// ---------------- k2: per-channel 512^3 bf16 GEMM, 512 threads / 8 waves -----
__launch_bounds__(512, 4)
__global__ void k2_einsum(const unsigned short* __restrict__ left_t,
                          const unsigned short* __restrict__ right_bt,
                          unsigned short* __restrict__ tmpg) {
  __shared__ __align__(16) unsigned short Sm[128 * 132];  // Al/Bl overlaid by Cl
  unsigned short* Al = Sm;             // 128*32
  unsigned short* Bl = Sm + 128 * 32;  // 128*32
  unsigned short* Cl = Sm;             // 128*132 restage
  const int t = threadIdx.x;
  const int d = blockIdx.y;
  const int i0 = (blockIdx.x >> 2) << 7;
  const int k0 = (blockIdx.x & 3) << 7;
  const unsigned short* Ag = left_t   + (long)d * PP;  // [i][j]
  const unsigned short* Bg = right_bt + (long)d * PP;  // [k][j]  (B^T)
  const int lane = t & 63, w = t >> 6;
  const int ln = lane & 15, q8 = lane >> 4;
  const int wm = (w >> 2) << 6, wn = (w & 3) << 5;     // 64x32 per-wave tile
  const int sr = t >> 2, sc = t & 3;

  floatx4 acc[4][2] = {};
  for (int j0 = 0; j0 < NN; j0 += 32) {
    gload_lds16(Ag + (long)(i0 + sr) * NN + j0 + sc * 8, &Al[t * 8]);
    gload_lds16(Bg + (long)(k0 + sr) * NN + j0 + sc * 8, &Bl[t * 8]);
    __syncthreads();
    short8 a[4], b[2];
    #pragma unroll
    for (int i = 0; i < 4; ++i)
      a[i] = *(const short8*)&Al[(wm + i * 16 + ln) * 32 + q8 * 8];
    #pragma unroll
    for (int j = 0; j < 2; ++j)
      b[j] = *(const short8*)&Bl[(wn + j * 16 + ln) * 32 + q8 * 8];
    #pragma unroll
    for (int i = 0; i < 4; ++i)
      #pragma unroll
      for (int j = 0; j < 2; ++j)
        acc[i][j] = __builtin_amdgcn_mfma_f32_16x16x32_bf16(a[i], b[j], acc[i][j], 0, 0, 0);
    __syncthreads();
  }
  // restage C through LDS -> coalesced bf16 stores
  #pragma unroll
  for (int i = 0; i < 4; ++i)
    #pragma unroll
    for (int j = 0; j < 2; ++j) {
      int n = wn + j * 16 + ln;
      #pragma unroll
      for (int r = 0; r < 4; ++r)
        Cl[(wm + i * 16 + q8 * 4 + r) * 132 + n] = f2bf(acc[i][j][r]);
    }
  __syncthreads();
  unsigned short* Og = tmpg + (long)d * PP;
  #pragma unroll
  for (int it = 0; it < 4; ++it) {
    int flat = it * 512 + t;
    int m = flat >> 4, c = flat & 15;
    *(short8*)(Og + (long)(i0 + m) * NN + k0 + c * 8) = *(const short8*)&Cl[m * 132 + c * 8];
  }
}

// ---------------- k3: out[p][e] = sum_d (tmpg*gate)[d][p]*wo[d][e] + b_o ------
// Transpose-on-stage into Tl[p][d] (pitch 144 shorts), with XOR bank swizzle:
// column (in 16B units) is XORed with bits of p so the stage writes spread
// across banks (was a 16-way conflict: bank depended only on rp).
// swizzle (word units): wcol' = wcol ^ (((p>>3)&7)<<3) ^ (((p>>6)&1)<<2)
__launch_bounds__(512, 4)
__global__ void k3_out(const unsigned short* __restrict__ tmpg,
                       const unsigned short* __restrict__ gate_t,
                       const unsigned short* __restrict__ wt,
                       const float* __restrict__ b_o,
                       float* __restrict__ out) {
  __shared__ __align__(16) unsigned short Tl[128 * 144];  // [p][d], 36.9 KB
  unsigned int* TlU = (unsigned int*)Tl;                  // pitch 72 uints
  const int t = threadIdx.x;
  const long p0 = (long)blockIdx.x << 7;
  const unsigned short* wo = wt + 5 * 16384;

  #pragma unroll
  for (int it = 0; it < 2; ++it) {
    int flat = it * 512 + t;
    int rp = flat >> 4;      // d-pair 0..63
    int c  = flat & 15;      // 16B chunk along p
    const unsigned short* ra = tmpg   + (long)(2 * rp) * PP + p0 + c * 8;
    const unsigned short* ga = gate_t + (long)(2 * rp) * PP + p0 + c * 8;
    uintx4 xa = *(const uintx4*)ra;
    uintx4 xb = *(const uintx4*)(ra + PP);
    uintx4 ya = *(const uintx4*)ga;
    uintx4 yb = *(const uintx4*)(ga + PP);
    int sw = ((c & 7) << 3) ^ ((c >> 3) << 2);   // p>>3 == c for this stage
    #pragma unroll
    for (int cc = 0; cc < 4; ++cc) {
      float pl = __uint_as_float(xa[cc] << 16) * __uint_as_float(ya[cc] << 16);
      float ph = __uint_as_float(xa[cc] & 0xffff0000u) * __uint_as_float(ya[cc] & 0xffff0000u);
      float ql = __uint_as_float(xb[cc] << 16) * __uint_as_float(yb[cc] << 16);
      float qh = __uint_as_float(xb[cc] & 0xffff0000u) * __uint_as_float(yb[cc] & 0xffff0000u);
      int p = c * 8 + 2 * cc;
      TlU[p * 72 + (rp ^ sw)]       = pkbf2(pl, ql);   // (d=2rp, d=2rp+1) at pos p
      TlU[(p + 1) * 72 + (rp ^ sw)] = pkbf2(ph, qh);   // p and p+1 share p>>3
    }
  }
  __syncthreads();

  const int lane = t & 63, w = t >> 6;
  const int ln = lane & 15, q8 = lane >> 4;
  const int wm = (w >> 2) << 6, wn = (w & 3) << 5;    // 64x32 per-wave tile

  floatx4 acc[4][2] = {};
  #pragma unroll
  for (int ks = 0; ks < 4; ++ks) {
    short8 a[4], b[2];
    #pragma unroll
    for (int i = 0; i < 4; ++i) {
      int p = wm + i * 16 + ln;
      int swh = (((p >> 3) & 7) << 4) ^ (((p >> 6) & 1) << 3);  // short units
      a[i] = *(const short8*)&Tl[p * 144 + ((ks * 32 + q8 * 8) ^ swh)];
    }
    #pragma unroll
    for (int j = 0; j < 2; ++j)
      b[j] = *(const short8*)(wo + (wn + j * 16 + ln) * 128 + ks * 32 + q8 * 8);
    #pragma unroll
    for (int i = 0; i < 4; ++i)
      #pragma unroll
      for (int j = 0; j < 2; ++j)
        acc[i][j] = __builtin_amdgcn_mfma_f32_16x16x32_bf16(a[i], b[j], acc[i][j], 0, 0, 0);
  }
  #pragma unroll
  for (int j = 0; j < 2; ++j) {
    int eg = wn + j * 16 + ln;
    float bias = b_o[eg];
    #pragma unroll
    for (int i = 0; i < 4; ++i)
      #pragma unroll
      for (int r = 0; r < 4; ++r) {
        int m = wm + i * 16 + q8 * 4 + r;
        out[(p0 + m) * DD + eg] = acc[i][j][r] + bias;
      }
  }
}

extern "C" void kernel_launch(void* const* d_in, const int* in_sizes, int n_in,
                              void* d_out, int out_size, void* d_ws, size_t ws_size,
                              hipStream_t stream) {
  const float* pair = (const float*)d_in[0];
  const float* pmask = (const float*)d_in[1];
  const float* ln_g = (const float*)d_in[2];
  const float* ln_b = (const float*)d_in[3];
  const float* w_lp = (const float*)d_in[4];
  const float* b_lp = (const float*)d_in[5];
  const float* w_lg = (const float*)d_in[6];
  const float* b_lg = (const float*)d_in[7];
  const float* w_rp = (const float*)d_in[8];
  const float* b_rp = (const float*)d_in[9];
  const float* w_rg = (const float*)d_in[10];
  const float* b_rg = (const float*)d_in[11];
  const float* w_g  = (const float*)d_in[12];
  const float* b_g  = (const float*)d_in[13];
  const float* w_o  = (const float*)d_in[14];
  const float* b_o  = (const float*)d_in[15];
  float* out = (float*)d_out;

  // workspace: wt(192KB) + xln (later tmpg) + left_t + right_bt + gate_t
  char* ws = (char*)d_ws;
  unsigned short* wt       = (unsigned short*)ws;
  unsigned short* xln      = (unsigned short*)(ws + 196608);
  unsigned short* left_t   = xln      + (size_t)PP * DD;
  unsigned short* right_bt = left_t   + (size_t)PP * DD;
  unsigned short* gate_t   = right_bt + (size_t)PP * DD;
  unsigned short* tmpg     = xln;   // xln dead after k1b

  k0_prep<<<dim3(64, 6), 256, 0, stream>>>(w_lp, w_lg, w_rp, w_rg, w_g, w_o, wt);
  k1a_ln<<<dim3(2048), 256, 0, stream>>>(pair, ln_g, ln_b, xln);
  k1b_proj<<<dim3(2048, 3), 512, 0, stream>>>(xln, pmask, wt,
      b_lp, b_lg, b_rp, b_rg, b_g, left_t, right_bt, gate_t);
  k2_einsum<<<dim3(16, 128), 512, 0, stream>>>(left_t, right_bt, tmpg);
  k3_out<<<dim3(2048), 512, 0, stream>>>(tmpg, gate_t, wt, b_o, out);
}

// Round 2
// 513.182 us; speedup vs baseline: 1.0102x; 1.0098x over previous
//
#include <hip/hip_runtime.h>

#define NN 512
#define DD 128
#define PP (NN*NN)   // 262144 positions

typedef __attribute__((ext_vector_type(8))) short short8;
typedef __attribute__((ext_vector_type(4))) float floatx4;
typedef __attribute__((ext_vector_type(4))) unsigned int uintx4;

__device__ __forceinline__ unsigned short f2bf(float f) {
  unsigned int u = __float_as_uint(f);
  u += 0x7fffu + ((u >> 16) & 1u);          // RNE
  return (unsigned short)(u >> 16);
}
// packed f32x2 -> bf16x2 (hardware RNE), low half <- first arg
__device__ __forceinline__ unsigned int pkbf2(float lo, float hi) {
  unsigned int r;
  asm("v_cvt_pk_bf16_f32 %0, %1, %2" : "=v"(r) : "v"(lo), "v"(hi));
  return r;
}
__device__ __forceinline__ float sigm(float x) {
  return 1.f / (1.f + __expf(-x));
}

// async global->LDS, 16B per lane. LDS dest must be wave-uniform base + lane*16.
__device__ __forceinline__ void gload_lds16(const unsigned short* g, unsigned short* l) {
  __builtin_amdgcn_global_load_lds(
      (const __attribute__((address_space(1))) unsigned int*)g,
      (__attribute__((address_space(3))) unsigned int*)l, 16, 0, 0);
}

// ---------------- k0: weights f32 [d][e] -> bf16 [m][e][d] ----------------
__global__ void k0_prep(const float* __restrict__ wlp, const float* __restrict__ wlg,
                        const float* __restrict__ wrp, const float* __restrict__ wrg,
                        const float* __restrict__ wg,  const float* __restrict__ wo,
                        unsigned short* __restrict__ wt) {
  const float* src[6] = {wlp, wlg, wrp, wrg, wg, wo};
  int m = blockIdx.y;
  int idx = blockIdx.x * 256 + threadIdx.x;   // 0..16383
  int d = idx >> 7, e = idx & 127;
  wt[m * 16384 + e * 128 + d] = f2bf(src[m][d * 128 + e]);
}

// ---------------- k1a: LayerNorm pair f32 -> xln bf16 [p][d] -----------------
__launch_bounds__(256, 4)
__global__ void k1a_ln(const float* __restrict__ pair,
                       const float* __restrict__ lng, const float* __restrict__ lnb,
                       unsigned short* __restrict__ xln) {
  const int t = threadIdx.x;
  const long p0 = (long)blockIdx.x << 7;
  const int r = t >> 1, h = t & 1;
  const float* row = pair + (p0 + r) * DD + h * 64;
  floatx4 v[16];
  float s = 0.f, s2 = 0.f;
  #pragma unroll
  for (int c = 0; c < 16; ++c) {
    v[c] = *(const floatx4*)(row + c * 4);
    s  += v[c].x + v[c].y + v[c].z + v[c].w;
    s2 += v[c].x * v[c].x + v[c].y * v[c].y + v[c].z * v[c].z + v[c].w * v[c].w;
  }
  s  += __shfl_xor(s, 1);
  s2 += __shfl_xor(s2, 1);
  float mu = s * (1.f / 128.f);
  float var = s2 * (1.f / 128.f) - mu * mu;
  float rs = rsqrtf(var + 1e-5f);
  unsigned short* orow = xln + (p0 + r) * DD + h * 64;
  #pragma unroll
  for (int c2 = 0; c2 < 8; ++c2) {
    floatx4 g0 = *(const floatx4*)(lng + h * 64 + c2 * 8);
    floatx4 g1 = *(const floatx4*)(lng + h * 64 + c2 * 8 + 4);
    floatx4 b0 = *(const floatx4*)(lnb + h * 64 + c2 * 8);
    floatx4 b1 = *(const floatx4*)(lnb + h * 64 + c2 * 8 + 4);
    floatx4 a = v[2 * c2], b = v[2 * c2 + 1];
    uintx4 u;
    u[0] = pkbf2((a.x - mu) * rs * g0.x + b0.x, (a.y - mu) * rs * g0.y + b0.y);
    u[1] = pkbf2((a.z - mu) * rs * g0.z + b0.z, (a.w - mu) * rs * g0.w + b0.w);
    u[2] = pkbf2((b.x - mu) * rs * g1.x + b1.x, (b.y - mu) * rs * g1.y + b1.y);
    u[3] = pkbf2((b.z - mu) * rs * g1.z + b1.z, (b.w - mu) * rs * g1.w + b1.w);
    *(uintx4*)(orow + c2 * 8) = u;
  }
}

// ---------------- k1b: projections, 2-phase double-buffered staged GEMM ------
// unit 0: left_t[e][p], unit 1: right_bt[e][k*512+j], unit 2: gate_t[e][p]
// 8 waves x (64m x 32e) subtiles. Double-buffered LDS sets; next tile's
// global_load_lds issued BEFORE compute so the vmcnt(0) drain inside the
// trailing __syncthreads lands after the MFMA work (T3 minimum-2-phase).
__launch_bounds__(512, 4)
__global__ void k1b_proj(const unsigned short* __restrict__ xln,
                         const float* __restrict__ pmask,
                         const unsigned short* __restrict__ wt,
                         const float* __restrict__ b_lp, const float* __restrict__ b_lg,
                         const float* __restrict__ b_rp, const float* __restrict__ b_rg,
                         const float* __restrict__ b_g,
                         unsigned short* __restrict__ left_t,
                         unsigned short* __restrict__ right_bt,
                         unsigned short* __restrict__ gate_t) {
  // 2 sets x (Al 4096 + Bp 4096 + Bg 4096) shorts = 49152 B; epilogue stg
  // (8 waves x 2176 shorts = 34.8 KB) overlays the sets after the last barrier.
  __shared__ __align__(16) unsigned short Sm[24576];
  __shared__ float Mlds[128];

  const int t = threadIdx.x;
  const int unit = blockIdx.y;
  const int q = blockIdx.x;

  int j0 = 0, kk = 0;
  long p0 = 0, soff;
  if (unit == 1) {
    j0 = (q >> 9) << 7; kk = q & 511;
    soff = (long)kk * NN + j0;
  } else {
    p0 = (long)q << 7;
    soff = p0;
  }
  auto arow = [&](int r) -> long {
    return (unit == 1) ? ((long)(j0 + r) * NN + kk) : (p0 + r);
  };

  if (unit < 2 && t < 128) Mlds[t] = pmask[arow(t)];

  const unsigned short* wA = wt + (unit == 0 ? 0 : unit == 1 ? 2 : 4) * 16384;
  const unsigned short* wB = wt + (unit == 0 ? 1 : 3) * 16384;  // unused for unit 2

  const int lane = t & 63, w = t >> 6;            // 8 waves
  const int ln = lane & 15, q8 = lane >> 4;
  const int wm = (w >> 2) << 6, we = (w & 3) << 5; // 64x32 per-wave tile
  const int sr = t >> 2, sc = t & 3;               // staging: one 16B chunk/thread

  const long aBase = arow(sr) * DD + sc * 8;       // invariant part of A address

  auto STAGE = [&](int set, int kc) {
    unsigned short* base = Sm + set * 12288;
    gload_lds16(xln + aBase + kc * 32,            &base[t * 8]);
    gload_lds16(wA + sr * 128 + kc * 32 + sc * 8, &base[4096 + t * 8]);
    if (unit < 2)
      gload_lds16(wB + sr * 128 + kc * 32 + sc * 8, &base[8192 + t * 8]);
  };

  floatx4 aP[4][2] = {}, aG[4][2] = {};
  STAGE(0, 0);
  __syncthreads();
  #pragma unroll
  for (int kc = 0; kc < 4; ++kc) {
    const int cur = kc & 1;
    if (kc < 3) STAGE(cur ^ 1, kc + 1);          // prefetch next tile
    unsigned short* Al = Sm + cur * 12288;
    unsigned short* Bp = Al + 4096;
    unsigned short* Bg = Al + 8192;
    short8 a[4];
    #pragma unroll
    for (int i = 0; i < 4; ++i)
      a[i] = *(const short8*)&Al[(wm + i * 16 + ln) * 32 + q8 * 8];
    #pragma unroll
    for (int j = 0; j < 2; ++j) {
      short8 bpv = *(const short8*)&Bp[(we + j * 16 + ln) * 32 + q8 * 8];
      #pragma unroll
      for (int i = 0; i < 4; ++i)
        aP[i][j] = __builtin_amdgcn_mfma_f32_16x16x32_bf16(a[i], bpv, aP[i][j], 0, 0, 0);
    }
    if (unit < 2) {
      #pragma unroll
      for (int j = 0; j < 2; ++j) {
        short8 bgv = *(const short8*)&Bg[(we + j * 16 + ln) * 32 + q8 * 8];
        #pragma unroll
        for (int i = 0; i < 4; ++i)
          aG[i][j] = __builtin_amdgcn_mfma_f32_16x16x32_bf16(a[i], bgv, aG[i][j], 0, 0, 0);
      }
    }
    __syncthreads();   // drains this iteration's prefetch loads after compute
  }

  // epilogue -> per-wave stg (32 e-rows x 64 m-cols, pitch 68) -> coalesced store
  unsigned short* mystg = Sm + w * 2176;
  if (unit < 2) {
    const float* bpp = (unit == 0) ? b_lp : b_rp;
    const float* bgg = (unit == 0) ? b_lg : b_rg;
    #pragma unroll
    for (int j = 0; j < 2; ++j) {
      int eg = we + j * 16 + ln;
      float bp = bpp[eg], bg = bgg[eg];
      #pragma unroll
      for (int i = 0; i < 4; ++i) {
        float vv[4];
        #pragma unroll
        for (int r = 0; r < 4; ++r) {
          int m = wm + i * 16 + q8 * 4 + r;
          vv[r] = (aP[i][j][r] + bp) * sigm(aG[i][j][r] + bg) * Mlds[m];
        }
        unsigned int* du = (unsigned int*)&mystg[(j * 16 + ln) * 68 + i * 16 + q8 * 4];
        du[0] = pkbf2(vv[0], vv[1]);
        du[1] = pkbf2(vv[2], vv[3]);
      }
    }
  } else {
    #pragma unroll
    for (int j = 0; j < 2; ++j) {
      int eg = we + j * 16 + ln;
      float bg = b_g[eg];
      #pragma unroll
      for (int i = 0; i < 4; ++i) {
        float vv[4];
        #pragma unroll
        for (int r = 0; r < 4; ++r)
          vv[r] = sigm(aP[i][j][r] + bg);
        unsigned int* du = (unsigned int*)&mystg[(j * 16 + ln) * 68 + i * 16 + q8 * 4];
        du[0] = pkbf2(vv[0], vv[1]);
        du[1] = pkbf2(vv[2], vv[3]);
      }
    }
  }

  unsigned short* dstbase = (unit == 0) ? left_t : (unit == 1 ? right_bt : gate_t);
  #pragma unroll
  for (int itr = 0; itr < 4; ++itr) {       // coalesced transposed store: rows = e
    int row = itr * 8 + (lane >> 3);        // 0..31
    int c = lane & 7;
    short8 vv = *(const short8*)&mystg[row * 68 + c * 8];
    long eg = we + row;
    *(short8*)(dstbase + eg * PP + soff + wm + c * 8) = vv;
  }
}

// ---------------- k2: per-channel 512^3 bf16 GEMM, 2-phase double-buffered ---
__launch_bounds__(512, 4)
__global__ void k2_einsum(const unsigned short* __restrict__ left_t,
                          const unsigned short* __restrict__ right_bt,
                          unsigned short* __restrict__ tmpg) {
  // 2 sets x (Al 4096 + Bl 4096) shorts = 32768 B; Cl restage (128x132 shorts
  // = 33792 B) overlays both sets after the final barrier.
  __shared__ __align__(16) unsigned short Sm[16896];
  unsigned short* Cl = Sm;
  const int t = threadIdx.x;
  const int d = blockIdx.y;
  const int i0 = (blockIdx.x >> 2) << 7;
  const int k0 = (blockIdx.x & 3) << 7;
  const unsigned short* Ag = left_t   + (long)d * PP;  // [i][j]
  const unsigned short* Bg = right_bt + (long)d * PP;  // [k][j]  (B^T)
  const int lane = t & 63, w = t >> 6;
  const int ln = lane & 15, q8 = lane >> 4;
  const int wm = (w >> 2) << 6, wn = (w & 3) << 5;     // 64x32 per-wave tile
  const int sr = t >> 2, sc = t & 3;

  const long aBase = (long)(i0 + sr) * NN + sc * 8;
  const long bBase = (long)(k0 + sr) * NN + sc * 8;

  auto STAGE = [&](int set, int jj) {
    gload_lds16(Ag + aBase + jj, &Sm[set * 8192 + t * 8]);
    gload_lds16(Bg + bBase + jj, &Sm[set * 8192 + 4096 + t * 8]);
  };

  floatx4 acc[4][2] = {};
  STAGE(0, 0);
  __syncthreads();
  for (int it = 0; it < 16; ++it) {
    const int cur = it & 1;
    if (it < 15) STAGE(cur ^ 1, (it + 1) * 32);      // prefetch next tile
    unsigned short* Al = Sm + cur * 8192;
    unsigned short* Bl = Al + 4096;
    short8 a[4], b[2];
    #pragma unroll
    for (int i = 0; i < 4; ++i)
      a[i] = *(const short8*)&Al[(wm + i * 16 + ln) * 32 + q8 * 8];
    #pragma unroll
    for (int j = 0; j < 2; ++j)
      b[j] = *(const short8*)&Bl[(wn + j * 16 + ln) * 32 + q8 * 8];
    #pragma unroll
    for (int i = 0; i < 4; ++i)
      #pragma unroll
      for (int j = 0; j < 2; ++j)
        acc[i][j] = __builtin_amdgcn_mfma_f32_16x16x32_bf16(a[i], b[j], acc[i][j], 0, 0, 0);
    __syncthreads();   // drains this iteration's prefetch loads after compute
  }
  // restage C through LDS -> coalesced bf16 stores
  #pragma unroll
  for (int i = 0; i < 4; ++i)
    #pragma unroll
    for (int j = 0; j < 2; ++j) {
      int n = wn + j * 16 + ln;
      #pragma unroll
      for (int r = 0; r < 4; ++r)
        Cl[(wm + i * 16 + q8 * 4 + r) * 132 + n] = f2bf(acc[i][j][r]);
    }
  __syncthreads();
  unsigned short* Og = tmpg + (long)d * PP;
  #pragma unroll
  for (int it = 0; it < 4; ++it) {
    int flat = it * 512 + t;
    int m = flat >> 4, c = flat & 15;
    *(short8*)(Og + (long)(i0 + m) * NN + k0 + c * 8) = *(const short8*)&Cl[m * 132 + c * 8];
  }
}

// ---------------- k3: out[p][e] = sum_d (tmpg*gate)[d][p]*wo[d][e] + b_o ------
// Transpose-on-stage into Tl[p][d] (pitch 144 shorts), with XOR bank swizzle.
__launch_bounds__(512, 4)
__global__ void k3_out(const unsigned short* __restrict__ tmpg,
                       const unsigned short* __restrict__ gate_t,
                       const unsigned short* __restrict__ wt,
                       const float* __restrict__ b_o,
                       float* __restrict__ out) {
  __shared__ __align__(16) unsigned short Tl[128 * 144];  // [p][d], 36.9 KB
  unsigned int* TlU = (unsigned int*)Tl;                  // pitch 72 uints
  const int t = threadIdx.x;
  const long p0 = (long)blockIdx.x << 7;
  const unsigned short* wo = wt + 5 * 16384;

  #pragma unroll
  for (int it = 0; it < 2; ++it) {
    int flat = it * 512 + t;
    int rp = flat >> 4;      // d-pair 0..63
    int c  = flat & 15;      // 16B chunk along p
    const unsigned short* ra = tmpg   + (long)(2 * rp) * PP + p0 + c * 8;
    const unsigned short* ga = gate_t + (long)(2 * rp) * PP + p0 + c * 8;
    uintx4 xa = *(const uintx4*)ra;
    uintx4 xb = *(const uintx4*)(ra + PP);
    uintx4 ya = *(const uintx4*)ga;
    uintx4 yb = *(const uintx4*)(ga + PP);
    int sw = ((c & 7) << 3) ^ ((c >> 3) << 2);   // p>>3 == c for this stage
    #pragma unroll
    for (int cc = 0; cc < 4; ++cc) {
      float pl = __uint_as_float(xa[cc] << 16) * __uint_as_float(ya[cc] << 16);
      float ph = __uint_as_float(xa[cc] & 0xffff0000u) * __uint_as_float(ya[cc] & 0xffff0000u);
      float ql = __uint_as_float(xb[cc] << 16) * __uint_as_float(yb[cc] << 16);
      float qh = __uint_as_float(xb[cc] & 0xffff0000u) * __uint_as_float(yb[cc] & 0xffff0000u);
      int p = c * 8 + 2 * cc;
      TlU[p * 72 + (rp ^ sw)]       = pkbf2(pl, ql);   // (d=2rp, d=2rp+1) at pos p
      TlU[(p + 1) * 72 + (rp ^ sw)] = pkbf2(ph, qh);   // p and p+1 share p>>3
    }
  }
  __syncthreads();

  const int lane = t & 63, w = t >> 6;
  const int ln = lane & 15, q8 = lane >> 4;
  const int wm = (w >> 2) << 6, wn = (w & 3) << 5;    // 64x32 per-wave tile

  floatx4 acc[4][2] = {};
  #pragma unroll
  for (int ks = 0; ks < 4; ++ks) {
    short8 a[4], b[2];
    #pragma unroll
    for (int i = 0; i < 4; ++i) {
      int p = wm + i * 16 + ln;
      int swh = (((p >> 3) & 7) << 4) ^ (((p >> 6) & 1) << 3);  // short units
      a[i] = *(const short8*)&Tl[p * 144 + ((ks * 32 + q8 * 8) ^ swh)];
    }
    #pragma unroll
    for (int j = 0; j < 2; ++j)
      b[j] = *(const short8*)(wo + (wn + j * 16 + ln) * 128 + ks * 32 + q8 * 8);
    #pragma unroll
    for (int i = 0; i < 4; ++i)
      #pragma unroll
      for (int j = 0; j < 2; ++j)
        acc[i][j] = __builtin_amdgcn_mfma_f32_16x16x32_bf16(a[i], b[j], acc[i][j], 0, 0, 0);
  }
  #pragma unroll
  for (int j = 0; j < 2; ++j) {
    int eg = wn + j * 16 + ln;
    float bias = b_o[eg];
    #pragma unroll
    for (int i = 0; i < 4; ++i)
      #pragma unroll
      for (int r = 0; r < 4; ++r) {
        int m = wm + i * 16 + q8 * 4 + r;
        out[(p0 + m) * DD + eg] = acc[i][j][r] + bias;
      }
  }
}

extern "C" void kernel_launch(void* const* d_in, const int* in_sizes, int n_in,
                              void* d_out, int out_size, void* d_ws, size_t ws_size,
                              hipStream_t stream) {
  const float* pair = (const float*)d_in[0];
  const float* pmask = (const float*)d_in[1];
  const float* ln_g = (const float*)d_in[2];
  const float* ln_b = (const float*)d_in[3];
  const float* w_lp = (const float*)d_in[4];
  const float* b_lp = (const float*)d_in[5];
  const float* w_lg = (const float*)d_in[6];
  const float* b_lg = (const float*)d_in[7];
  const float* w_rp = (const float*)d_in[8];
  const float* b_rp = (const float*)d_in[9];
  const float* w_rg = (const float*)d_in[10];
  const float* b_rg = (const float*)d_in[11];
  const float* w_g  = (const float*)d_in[12];
  const float* b_g  = (const float*)d_in[13];
  const float* w_o  = (const float*)d_in[14];
  const float* b_o  = (const float*)d_in[15];
  float* out = (float*)d_out;

  // workspace: wt(192KB) + xln (later tmpg) + left_t + right_bt + gate_t
  char* ws = (char*)d_ws;
  unsigned short* wt       = (unsigned short*)ws;
  unsigned short* xln      = (unsigned short*)(ws + 196608);
  unsigned short* left_t   = xln      + (size_t)PP * DD;
  unsigned short* right_bt = left_t   + (size_t)PP * DD;
  unsigned short* gate_t   = right_bt + (size_t)PP * DD;
  unsigned short* tmpg     = xln;   // xln dead after k1b

  k0_prep<<<dim3(64, 6), 256, 0, stream>>>(w_lp, w_lg, w_rp, w_rg, w_g, w_o, wt);
  k1a_ln<<<dim3(2048), 256, 0, stream>>>(pair, ln_g, ln_b, xln);
  k1b_proj<<<dim3(2048, 3), 512, 0, stream>>>(xln, pmask, wt,
      b_lp, b_lg, b_rp, b_rg, b_g, left_t, right_bt, gate_t);
  k2_einsum<<<dim3(16, 128), 512, 0, stream>>>(left_t, right_bt, tmpg);
  k3_out<<<dim3(2048), 512, 0, stream>>>(tmpg, gate_t, wt, b_o, out);
}

// Round 3
// 488.741 us; speedup vs baseline: 1.0608x; 1.0500x over previous
//
#include <hip/hip_runtime.h>

#define NN 512
#define DD 128
#define PP (NN*NN)   // 262144 positions

typedef __attribute__((ext_vector_type(8))) short short8;
typedef __attribute__((ext_vector_type(4))) float floatx4;
typedef __attribute__((ext_vector_type(4))) unsigned int uintx4;
typedef __attribute__((ext_vector_type(2))) unsigned int uintx2;

__device__ __forceinline__ unsigned short f2bf(float f) {
  unsigned int u = __float_as_uint(f);
  u += 0x7fffu + ((u >> 16) & 1u);          // RNE
  return (unsigned short)(u >> 16);
}
__device__ __forceinline__ float bf2f(unsigned short h) {
  return __uint_as_float(((unsigned int)h) << 16);
}
// packed f32x2 -> bf16x2 (hardware RNE), low half <- first arg
__device__ __forceinline__ unsigned int pkbf2(float lo, float hi) {
  unsigned int r;
  asm("v_cvt_pk_bf16_f32 %0, %1, %2" : "=v"(r) : "v"(lo), "v"(hi));
  return r;
}
__device__ __forceinline__ float sigm(float x) {
  return 1.f / (1.f + __expf(-x));
}

// async global->LDS, 16B per lane. LDS dest must be wave-uniform base + lane*16.
__device__ __forceinline__ void gload_lds16(const unsigned short* g, unsigned short* l) {
  __builtin_amdgcn_global_load_lds(
      (const __attribute__((address_space(1))) unsigned int*)g,
      (__attribute__((address_space(3))) unsigned int*)l, 16, 0, 0);
}

// ---------------- k0: weights f32 [d][e] -> bf16 [m][e][d] ----------------
__global__ void k0_prep(const float* __restrict__ wlp, const float* __restrict__ wlg,
                        const float* __restrict__ wrp, const float* __restrict__ wrg,
                        const float* __restrict__ wg,  const float* __restrict__ wo,
                        unsigned short* __restrict__ wt) {
  const float* src[6] = {wlp, wlg, wrp, wrg, wg, wo};
  int m = blockIdx.y;
  int idx = blockIdx.x * 256 + threadIdx.x;   // 0..16383
  int d = idx >> 7, e = idx & 127;
  wt[m * 16384 + e * 128 + d] = f2bf(src[m][d * 128 + e]);
}

// ---------------- k1a: LayerNorm pair f32 -> xln bf16 [p][d] -----------------
// Coalesced layout: 32 lanes per row (each lane owns 4 floats), wave = 2 rows.
// Every global load instr covers 1KB contiguous; every store 512B contiguous.
// Row reduction via shfl_xor tree (masks 1..16 stay within the 32-lane group).
__launch_bounds__(256, 8)
__global__ void k1a_ln(const float* __restrict__ pair,
                       const float* __restrict__ lng, const float* __restrict__ lnb,
                       unsigned short* __restrict__ xln) {
  const int t = threadIdx.x;
  const int sub = t & 31;                       // float4 slot within row
  const long row0 = (long)blockIdx.x * 128 + (t >> 5);  // 8 rows per 256t pass
  const floatx4 g4 = *(const floatx4*)(lng + sub * 4);
  const floatx4 b4 = *(const floatx4*)(lnb + sub * 4);
  const float* src = pair + row0 * DD + sub * 4;
  unsigned short* dst = xln + row0 * DD + sub * 4;
  floatx4 vn = *(const floatx4*)src;
  #pragma unroll
  for (int pass = 0; pass < 16; ++pass) {
    floatx4 v = vn;
    if (pass < 15) vn = *(const floatx4*)(src + (pass + 1) * 8 * DD);
    float s  = v.x + v.y + v.z + v.w;
    float s2 = v.x * v.x + v.y * v.y + v.z * v.z + v.w * v.w;
    #pragma unroll
    for (int m = 1; m < 32; m <<= 1) {
      s  += __shfl_xor(s, m);
      s2 += __shfl_xor(s2, m);
    }
    float mu = s * (1.f / 128.f);
    float rs = rsqrtf(s2 * (1.f / 128.f) - mu * mu + 1e-5f);
    uintx2 o;
    o[0] = pkbf2((v.x - mu) * rs * g4.x + b4.x, (v.y - mu) * rs * g4.y + b4.y);
    o[1] = pkbf2((v.z - mu) * rs * g4.z + b4.z, (v.w - mu) * rs * g4.w + b4.w);
    *(uintx2*)(dst + pass * 8 * DD) = o;
  }
}

// ---------------- k1b: projections, 2-phase double-buffered staged GEMM ------
// unit 0: left_t[e][p], unit 1: right_bt[e][k*512+j], unit 2: gate_t[e][p]
__launch_bounds__(512, 4)
__global__ void k1b_proj(const unsigned short* __restrict__ xln,
                         const float* __restrict__ pmask,
                         const unsigned short* __restrict__ wt,
                         const float* __restrict__ b_lp, const float* __restrict__ b_lg,
                         const float* __restrict__ b_rp, const float* __restrict__ b_rg,
                         const float* __restrict__ b_g,
                         unsigned short* __restrict__ left_t,
                         unsigned short* __restrict__ right_bt,
                         unsigned short* __restrict__ gate_t) {
  // 2 sets x (Al 4096 + Bp 4096 + Bg 4096) shorts = 49152 B; epilogue stg
  // (8 waves x 2176 shorts = 34.8 KB) overlays the sets after the last barrier.
  __shared__ __align__(16) unsigned short Sm[24576];
  __shared__ float Mlds[128];

  const int t = threadIdx.x;
  const int unit = blockIdx.y;
  const int q = blockIdx.x;

  int j0 = 0, kk = 0;
  long p0 = 0, soff;
  if (unit == 1) {
    j0 = (q >> 9) << 7; kk = q & 511;
    soff = (long)kk * NN + j0;
  } else {
    p0 = (long)q << 7;
    soff = p0;
  }
  auto arow = [&](int r) -> long {
    return (unit == 1) ? ((long)(j0 + r) * NN + kk) : (p0 + r);
  };

  if (unit < 2 && t < 128) Mlds[t] = pmask[arow(t)];

  const unsigned short* wA = wt + (unit == 0 ? 0 : unit == 1 ? 2 : 4) * 16384;
  const unsigned short* wB = wt + (unit == 0 ? 1 : 3) * 16384;  // unused for unit 2

  const int lane = t & 63, w = t >> 6;            // 8 waves
  const int ln = lane & 15, q8 = lane >> 4;
  const int wm = (w >> 2) << 6, we = (w & 3) << 5; // 64x32 per-wave tile
  const int sr = t >> 2, sc = t & 3;               // staging: one 16B chunk/thread

  const long aBase = arow(sr) * DD + sc * 8;       // invariant part of A address

  auto STAGE = [&](int set, int kc) {
    unsigned short* base = Sm + set * 12288;
    gload_lds16(xln + aBase + kc * 32,            &base[t * 8]);
    gload_lds16(wA + sr * 128 + kc * 32 + sc * 8, &base[4096 + t * 8]);
    if (unit < 2)
      gload_lds16(wB + sr * 128 + kc * 32 + sc * 8, &base[8192 + t * 8]);
  };

  floatx4 aP[4][2] = {}, aG[4][2] = {};
  STAGE(0, 0);
  __syncthreads();
  #pragma unroll
  for (int kc = 0; kc < 4; ++kc) {
    const int cur = kc & 1;
    if (kc < 3) STAGE(cur ^ 1, kc + 1);          // prefetch next tile
    unsigned short* Al = Sm + cur * 12288;
    unsigned short* Bp = Al + 4096;
    unsigned short* Bg = Al + 8192;
    short8 a[4];
    #pragma unroll
    for (int i = 0; i < 4; ++i)
      a[i] = *(const short8*)&Al[(wm + i * 16 + ln) * 32 + q8 * 8];
    #pragma unroll
    for (int j = 0; j < 2; ++j) {
      short8 bpv = *(const short8*)&Bp[(we + j * 16 + ln) * 32 + q8 * 8];
      #pragma unroll
      for (int i = 0; i < 4; ++i)
        aP[i][j] = __builtin_amdgcn_mfma_f32_16x16x32_bf16(a[i], bpv, aP[i][j], 0, 0, 0);
    }
    if (unit < 2) {
      #pragma unroll
      for (int j = 0; j < 2; ++j) {
        short8 bgv = *(const short8*)&Bg[(we + j * 16 + ln) * 32 + q8 * 8];
        #pragma unroll
        for (int i = 0; i < 4; ++i)
          aG[i][j] = __builtin_amdgcn_mfma_f32_16x16x32_bf16(a[i], bgv, aG[i][j], 0, 0, 0);
      }
    }
    __syncthreads();   // drains this iteration's prefetch loads after compute
  }

  // epilogue -> per-wave stg (32 e-rows x 64 m-cols, pitch 68) -> coalesced store
  unsigned short* mystg = Sm + w * 2176;
  if (unit < 2) {
    const float* bpp = (unit == 0) ? b_lp : b_rp;
    const float* bgg = (unit == 0) ? b_lg : b_rg;
    #pragma unroll
    for (int j = 0; j < 2; ++j) {
      int eg = we + j * 16 + ln;
      float bp = bpp[eg], bg = bgg[eg];
      #pragma unroll
      for (int i = 0; i < 4; ++i) {
        float vv[4];
        #pragma unroll
        for (int r = 0; r < 4; ++r) {
          int m = wm + i * 16 + q8 * 4 + r;
          vv[r] = (aP[i][j][r] + bp) * sigm(aG[i][j][r] + bg) * Mlds[m];
        }
        unsigned int* du = (unsigned int*)&mystg[(j * 16 + ln) * 68 + i * 16 + q8 * 4];
        du[0] = pkbf2(vv[0], vv[1]);
        du[1] = pkbf2(vv[2], vv[3]);
      }
    }
  } else {
    #pragma unroll
    for (int j = 0; j < 2; ++j) {
      int eg = we + j * 16 + ln;
      float bg = b_g[eg];
      #pragma unroll
      for (int i = 0; i < 4; ++i) {
        float vv[4];
        #pragma unroll
        for (int r = 0; r < 4; ++r)
          vv[r] = sigm(aP[i][j][r] + bg);
        unsigned int* du = (unsigned int*)&mystg[(j * 16 + ln) * 68 + i * 16 + q8 * 4];
        du[0] = pkbf2(vv[0], vv[1]);
        du[1] = pkbf2(vv[2], vv[3]);
      }
    }
  }

  unsigned short* dstbase = (unit == 0) ? left_t : (unit == 1 ? right_bt : gate_t);
  #pragma unroll
  for (int itr = 0; itr < 4; ++itr) {       // coalesced transposed store: rows = e
    int row = itr * 8 + (lane >> 3);        // 0..31
    int c = lane & 7;
    short8 vv = *(const short8*)&mystg[row * 68 + c * 8];
    long eg = we + row;
    *(short8*)(dstbase + eg * PP + soff + wm + c * 8) = vv;
  }
}

// ---------------- k2: per-channel 512^3 bf16 GEMM + fused gate ---------------
// Writes tmpg pre-gated: tmpg[d][i,k] = (left@right^T)[i,k] * gate[d][i,k]
__launch_bounds__(512, 4)
__global__ void k2_einsum(const unsigned short* __restrict__ left_t,
                          const unsigned short* __restrict__ right_bt,
                          const unsigned short* __restrict__ gate_t,
                          unsigned short* __restrict__ tmpg) {
  // 2 sets x (Al 4096 + Bl 4096) shorts = 32768 B; Cl restage (128x132 shorts
  // = 33792 B) overlays both sets after the final barrier.
  __shared__ __align__(16) unsigned short Sm[16896];
  unsigned short* Cl = Sm;
  const int t = threadIdx.x;
  const int d = blockIdx.y;
  const int i0 = (blockIdx.x >> 2) << 7;
  const int k0 = (blockIdx.x & 3) << 7;
  const unsigned short* Ag = left_t   + (long)d * PP;  // [i][j]
  const unsigned short* Bg = right_bt + (long)d * PP;  // [k][j]  (B^T)
  const unsigned short* Gg = gate_t   + (long)d * PP;  // [i][k]
  const int lane = t & 63, w = t >> 6;
  const int ln = lane & 15, q8 = lane >> 4;
  const int wm = (w >> 2) << 6, wn = (w & 3) << 5;     // 64x32 per-wave tile
  const int sr = t >> 2, sc = t & 3;

  const long aBase = (long)(i0 + sr) * NN + sc * 8;
  const long bBase = (long)(k0 + sr) * NN + sc * 8;

  auto STAGE = [&](int set, int jj) {
    gload_lds16(Ag + aBase + jj, &Sm[set * 8192 + t * 8]);
    gload_lds16(Bg + bBase + jj, &Sm[set * 8192 + 4096 + t * 8]);
  };

  floatx4 acc[4][2] = {};
  STAGE(0, 0);
  __syncthreads();
  for (int it = 0; it < 16; ++it) {
    const int cur = it & 1;
    if (it < 15) STAGE(cur ^ 1, (it + 1) * 32);      // prefetch next tile
    unsigned short* Al = Sm + cur * 8192;
    unsigned short* Bl = Al + 4096;
    short8 a[4], b[2];
    #pragma unroll
    for (int i = 0; i < 4; ++i)
      a[i] = *(const short8*)&Al[(wm + i * 16 + ln) * 32 + q8 * 8];
    #pragma unroll
    for (int j = 0; j < 2; ++j)
      b[j] = *(const short8*)&Bl[(wn + j * 16 + ln) * 32 + q8 * 8];
    #pragma unroll
    for (int i = 0; i < 4; ++i)
      #pragma unroll
      for (int j = 0; j < 2; ++j)
        acc[i][j] = __builtin_amdgcn_mfma_f32_16x16x32_bf16(a[i], b[j], acc[i][j], 0, 0, 0);
    __syncthreads();   // drains this iteration's prefetch loads after compute
  }
  // gate in f32, restage C through LDS -> coalesced bf16 stores
  #pragma unroll
  for (int i = 0; i < 4; ++i)
    #pragma unroll
    for (int j = 0; j < 2; ++j) {
      int n = wn + j * 16 + ln;
      #pragma unroll
      for (int r = 0; r < 4; ++r) {
        int m = wm + i * 16 + q8 * 4 + r;
        float gf = bf2f(Gg[(long)(i0 + m) * NN + k0 + n]);
        Cl[m * 132 + n] = f2bf(acc[i][j][r] * gf);
      }
    }
  __syncthreads();
  unsigned short* Og = tmpg + (long)d * PP;
  #pragma unroll
  for (int it = 0; it < 4; ++it) {
    int flat = it * 512 + t;
    int m = flat >> 4, c = flat & 15;
    *(short8*)(Og + (long)(i0 + m) * NN + k0 + c * 8) = *(const short8*)&Cl[m * 132 + c * 8];
  }
}

// ---------------- k3: out[p][e] = sum_d tmpg[d][p]*wo[d][e] + b_o ------------
// tmpg is pre-gated by k2. Transpose-on-stage into Tl[p][d] (pitch 144 shorts)
// with XOR bank swizzle; repack is pure bit-ops (values already bf16).
__launch_bounds__(512, 4)
__global__ void k3_out(const unsigned short* __restrict__ tmpg,
                       const unsigned short* __restrict__ wt,
                       const float* __restrict__ b_o,
                       float* __restrict__ out) {
  __shared__ __align__(16) unsigned short Tl[128 * 144];  // [p][d], 36.9 KB
  unsigned int* TlU = (unsigned int*)Tl;                  // pitch 72 uints
  const int t = threadIdx.x;
  const long p0 = (long)blockIdx.x << 7;
  const unsigned short* wo = wt + 5 * 16384;

  #pragma unroll
  for (int it = 0; it < 2; ++it) {
    int flat = it * 512 + t;
    int rp = flat >> 4;      // d-pair 0..63
    int c  = flat & 15;      // 16B chunk along p
    const unsigned short* ra = tmpg + (long)(2 * rp) * PP + p0 + c * 8;
    uintx4 xa = *(const uintx4*)ra;          // row d=2rp
    uintx4 xb = *(const uintx4*)(ra + PP);   // row d=2rp+1
    int sw = ((c & 7) << 3) ^ ((c >> 3) << 2);   // p>>3 == c for this stage
    #pragma unroll
    for (int cc = 0; cc < 4; ++cc) {
      int p = c * 8 + 2 * cc;
      // (d=2rp -> low, d=2rp+1 -> high) for even/odd positions
      TlU[p * 72 + (rp ^ sw)]       = (xa[cc] & 0xffffu) | (xb[cc] << 16);
      TlU[(p + 1) * 72 + (rp ^ sw)] = (xa[cc] >> 16) | (xb[cc] & 0xffff0000u);
    }
  }
  __syncthreads();

  const int lane = t & 63, w = t >> 6;
  const int ln = lane & 15, q8 = lane >> 4;
  const int wm = (w >> 2) << 6, wn = (w & 3) << 5;    // 64x32 per-wave tile

  floatx4 acc[4][2] = {};
  #pragma unroll
  for (int ks = 0; ks < 4; ++ks) {
    short8 a[4], b[2];
    #pragma unroll
    for (int i = 0; i < 4; ++i) {
      int p = wm + i * 16 + ln;
      int swh = (((p >> 3) & 7) << 4) ^ (((p >> 6) & 1) << 3);  // short units
      a[i] = *(const short8*)&Tl[p * 144 + ((ks * 32 + q8 * 8) ^ swh)];
    }
    #pragma unroll
    for (int j = 0; j < 2; ++j)
      b[j] = *(const short8*)(wo + (wn + j * 16 + ln) * 128 + ks * 32 + q8 * 8);
    #pragma unroll
    for (int i = 0; i < 4; ++i)
      #pragma unroll
      for (int j = 0; j < 2; ++j)
        acc[i][j] = __builtin_amdgcn_mfma_f32_16x16x32_bf16(a[i], b[j], acc[i][j], 0, 0, 0);
  }
  #pragma unroll
  for (int j = 0; j < 2; ++j) {
    int eg = wn + j * 16 + ln;
    float bias = b_o[eg];
    #pragma unroll
    for (int i = 0; i < 4; ++i)
      #pragma unroll
      for (int r = 0; r < 4; ++r) {
        int m = wm + i * 16 + q8 * 4 + r;
        out[(p0 + m) * DD + eg] = acc[i][j][r] + bias;
      }
  }
}

extern "C" void kernel_launch(void* const* d_in, const int* in_sizes, int n_in,
                              void* d_out, int out_size, void* d_ws, size_t ws_size,
                              hipStream_t stream) {
  const float* pair = (const float*)d_in[0];
  const float* pmask = (const float*)d_in[1];
  const float* ln_g = (const float*)d_in[2];
  const float* ln_b = (const float*)d_in[3];
  const float* w_lp = (const float*)d_in[4];
  const float* b_lp = (const float*)d_in[5];
  const float* w_lg = (const float*)d_in[6];
  const float* b_lg = (const float*)d_in[7];
  const float* w_rp = (const float*)d_in[8];
  const float* b_rp = (const float*)d_in[9];
  const float* w_rg = (const float*)d_in[10];
  const float* b_rg = (const float*)d_in[11];
  const float* w_g  = (const float*)d_in[12];
  const float* b_g  = (const float*)d_in[13];
  const float* w_o  = (const float*)d_in[14];
  const float* b_o  = (const float*)d_in[15];
  float* out = (float*)d_out;

  // workspace: wt(192KB) + xln (later tmpg) + left_t + right_bt + gate_t
  char* ws = (char*)d_ws;
  unsigned short* wt       = (unsigned short*)ws;
  unsigned short* xln      = (unsigned short*)(ws + 196608);
  unsigned short* left_t   = xln      + (size_t)PP * DD;
  unsigned short* right_bt = left_t   + (size_t)PP * DD;
  unsigned short* gate_t   = right_bt + (size_t)PP * DD;
  unsigned short* tmpg     = xln;   // xln dead after k1b

  k0_prep<<<dim3(64, 6), 256, 0, stream>>>(w_lp, w_lg, w_rp, w_rg, w_g, w_o, wt);
  k1a_ln<<<dim3(2048), 256, 0, stream>>>(pair, ln_g, ln_b, xln);
  k1b_proj<<<dim3(2048, 3), 512, 0, stream>>>(xln, pmask, wt,
      b_lp, b_lg, b_rp, b_rg, b_g, left_t, right_bt, gate_t);
  k2_einsum<<<dim3(16, 128), 512, 0, stream>>>(left_t, right_bt, gate_t, tmpg);
  k3_out<<<dim3(2048), 512, 0, stream>>>(tmpg, wt, b_o, out);
}